// Round 2
// baseline (516.045 us; speedup 1.0000x reference)
//
#include <hip/hip_runtime.h>
#include <hip/hip_bf16.h>
#include <math.h>

// ToMe merge, B=64 T=577 C=1024, r=288 => unm = {token 0} always; output row 0 =
// token 0, row 1+j = mean(odd token 2j+1, all even tokens i>=1 with argmax_j
// cos(a_i,b_j) == j). Argmax must match the numpy reference EXACTLY (token
// flips blow absmax to ~7 vs threshold 0.104), so:
//   stage 1: 2-term bf16-split MFMA scores (err <= 7e-4) -> S matrix in ws
//   stage 2: exact f64 recheck of all cols within eps=3e-3 of each row max
// Input dtype is ambiguous from the harness (reference is f32; assert label
// says bf16 but that string is hardcoded) -> runtime dtype detector; every
// kernel branches wave-uniformly on the flag. rocprof FETCH_SIZE will reveal
// the world for the next round.

#define B_   64
#define T_   577
#define C_   1024
#define NA   289
#define NB   288

#define EPS_MARGIN 3e-3f

typedef __bf16 bf16x8 __attribute__((ext_vector_type(8)));
typedef float  floatx4 __attribute__((ext_vector_type(4)));
typedef unsigned short us8 __attribute__((ext_vector_type(8)));

union U8 { us8 s; bf16x8 v; uint4 u; };

// ws layout (bytes)
#define FLAG_OFF   0
#define RNORM_OFF  256                                   // double[B_*NB]
#define DST_OFF    (RNORM_OFF + B_*NB*8)                 // int[B_*NA]
#define S_OFF      (DST_OFF + ((B_*NA*4 + 255)/256)*256) // float[B_*NA*NB]

__device__ __forceinline__ float bflo(unsigned int u){ return __uint_as_float(u<<16); }
__device__ __forceinline__ float bfhi(unsigned int u){ return __uint_as_float(u & 0xFFFF0000u); }

// f32 -> bf16 bits, round-to-nearest-even (no NaN handling; data is gaussian)
__device__ __forceinline__ unsigned short f2bf(float f){
  unsigned int u = __float_as_uint(f);
  u = (u + 0x7FFFu + ((u>>16)&1u)) >> 16;
  return (unsigned short)u;
}

// ---------------------------------------------------------------------------
// dtype detector: even-indexed ushorts. bf16 world: every one is a bf16 value
// with exponent-field in [96,143] (gaussian data). f32 world: they are low
// mantissa halves -> uniform bits, ~19% in range. 512 samples, threshold 320.
// flag = 1 -> input is f32.
// ---------------------------------------------------------------------------
__global__ void k_detect(const unsigned short* __restrict__ xs,
                         unsigned int* __restrict__ flag) {
  int lane = threadIdx.x;
  int cnt = 0;
#pragma unroll
  for (int t = 0; t < 8; ++t) {
    unsigned int u = xs[(lane * 8 + t) * 2];
    unsigned int e = (u >> 7) & 0xFF;
    if (e >= 96 && e <= 143) cnt++;
  }
#pragma unroll
  for (int d = 32; d >= 1; d >>= 1) cnt += __shfl_xor(cnt, d, 64);
  if (lane == 0) *flag = (cnt < 320) ? 1u : 0u;
}

// ---------------------------------------------------------------------------
// load 16 consecutive elements (per-lane) as f32, either world
// ---------------------------------------------------------------------------
template<int F32>
__device__ __forceinline__ void load16(const void* x, size_t elem_off, float* v) {
  if (F32) {
    const float4* p = (const float4*)((const float*)x + elem_off);
    float4 a = p[0], b = p[1], c = p[2], d = p[3];
    v[0]=a.x; v[1]=a.y; v[2]=a.z; v[3]=a.w;
    v[4]=b.x; v[5]=b.y; v[6]=b.z; v[7]=b.w;
    v[8]=c.x; v[9]=c.y; v[10]=c.z; v[11]=c.w;
    v[12]=d.x; v[13]=d.y; v[14]=d.z; v[15]=d.w;
  } else {
    const uint4* p = (const uint4*)((const unsigned short*)x + elem_off);
    uint4 a = p[0], b = p[1];
    unsigned int w[8] = {a.x,a.y,a.z,a.w,b.x,b.y,b.z,b.w};
#pragma unroll
    for (int t = 0; t < 8; ++t) { v[2*t] = bflo(w[t]); v[2*t+1] = bfhi(w[t]); }
  }
}

template<int F32>
__device__ __forceinline__ void store16(void* out, size_t elem_off, const float* v) {
  if (F32) {
    float4* p = (float4*)((float*)out + elem_off);
    p[0] = make_float4(v[0],v[1],v[2],v[3]);
    p[1] = make_float4(v[4],v[5],v[6],v[7]);
    p[2] = make_float4(v[8],v[9],v[10],v[11]);
    p[3] = make_float4(v[12],v[13],v[14],v[15]);
  } else {
    unsigned int o[8];
#pragma unroll
    for (int t = 0; t < 8; ++t)
      o[t] = (unsigned int)f2bf(v[2*t]) | ((unsigned int)f2bf(v[2*t+1]) << 16);
    uint4* p = (uint4*)((unsigned short*)out + elem_off);
    p[0] = make_uint4(o[0],o[1],o[2],o[3]);
    p[1] = make_uint4(o[4],o[5],o[6],o[7]);
  }
}

// load 8 elems as split bf16 fragment (hi + lo); bf16 world: hi = data, lo unused
template<int F32>
__device__ __forceinline__ void load_frag(const void* x, size_t elem_off,
                                          bf16x8& h, bf16x8& l) {
  if (F32) {
    const float4* p = (const float4*)((const float*)x + elem_off);
    float4 f0 = p[0], f1 = p[1];
    float av[8] = {f0.x,f0.y,f0.z,f0.w,f1.x,f1.y,f1.z,f1.w};
    U8 hh, ll;
#pragma unroll
    for (int e = 0; e < 8; ++e) {
      unsigned short hb = f2bf(av[e]);
      float hf = __uint_as_float((unsigned int)hb << 16);
      hh.s[e] = hb;
      ll.s[e] = f2bf(av[e] - hf);   // exact residual (Sterbenz), then RNE
    }
    h = hh.v; l = ll.v;
  } else {
    U8 t; t.u = *(const uint4*)((const unsigned short*)x + elem_off);
    h = t.v; l = t.v;
  }
}

// ---------------------------------------------------------------------------
// Kernel: rnorm[b][j] = 1/||x[b,2j+1,:]|| in f64
// ---------------------------------------------------------------------------
template<int F32>
__device__ __forceinline__ void norms_body(const void* x, double* rnorm) {
  int wid = threadIdx.x >> 6, lane = threadIdx.x & 63;
  int gw = blockIdx.x * 4 + wid;           // grid = B*NB/4 exactly
  int b = gw / NB, j = gw - b * NB;
  float v[16];
  load16<F32>(x, (size_t)(b * T_ + 2 * j + 1) * C_ + lane * 16, v);
  double s = 0.0;
#pragma unroll
  for (int t = 0; t < 16; ++t) s += (double)v[t] * (double)v[t];
#pragma unroll
  for (int d = 32; d >= 1; d >>= 1) s += __shfl_xor(s, d, 64);
  if (lane == 0) rnorm[b * NB + j] = 1.0 / sqrt(s);
}
__global__ __launch_bounds__(256) void k_norms(const void* __restrict__ x,
                                               double* __restrict__ rnorm,
                                               const unsigned int* __restrict__ flag) {
  if (*flag) norms_body<1>(x, rnorm); else norms_body<0>(x, rnorm);
}

// ---------------------------------------------------------------------------
// Stage 1: S[b][i][j] = dot_split(a_i, b_j) * rnorm_j  via 16x16x32 bf16 MFMA.
// Wave handles 16 rows x 48 cols (3 j-tiles share the A fragment).
// A/B frag: row/col = lane&15, k = (lane>>4)*8 + e. C/D: col=lane&15,
// row=(lane>>4)*4+reg  [verified m89/m91].
// ---------------------------------------------------------------------------
template<int F32>
__device__ __forceinline__ void scores_body(const void* x, const double* rnormd,
                                            float* S) {
  int wid = threadIdx.x >> 6, lane = threadIdx.x & 63;
  int gw = blockIdx.x * 4 + wid;           // grid = B*19*6/4 = 1824 exactly
  int b = gw / 114, rem = gw - b * 114;
  int it = rem / 6, jg = rem - it * 6;
  int m = lane & 15, q = lane >> 4;

  int i0 = it * 16 + m;
  int rowA = 2 * i0; if (rowA > 576) rowA = 576;   // pad rows clamped, discarded at store
  size_t baseA = (size_t)(b * T_ + rowA) * C_ + q * 8;
  int j0 = jg * 48 + m;                            // <= 287 always
  size_t baseB0 = (size_t)(b * T_ + 2 * (j0)      + 1) * C_ + q * 8;
  size_t baseB1 = (size_t)(b * T_ + 2 * (j0 + 16) + 1) * C_ + q * 8;
  size_t baseB2 = (size_t)(b * T_ + 2 * (j0 + 32) + 1) * C_ + q * 8;

  floatx4 acc0 = {0,0,0,0}, acc1 = {0,0,0,0}, acc2 = {0,0,0,0};

  for (int ks = 0; ks < 32; ++ks) {
    size_t o = (size_t)ks * 32;
    bf16x8 ah, al, bh, bl;
    load_frag<F32>(x, baseA + o, ah, al);

    load_frag<F32>(x, baseB0 + o, bh, bl);
    if (F32) {
      acc0 = __builtin_amdgcn_mfma_f32_16x16x32_bf16(al, bh, acc0, 0,0,0);
      acc0 = __builtin_amdgcn_mfma_f32_16x16x32_bf16(ah, bl, acc0, 0,0,0);
    }
    acc0 = __builtin_amdgcn_mfma_f32_16x16x32_bf16(ah, bh, acc0, 0,0,0);

    load_frag<F32>(x, baseB1 + o, bh, bl);
    if (F32) {
      acc1 = __builtin_amdgcn_mfma_f32_16x16x32_bf16(al, bh, acc1, 0,0,0);
      acc1 = __builtin_amdgcn_mfma_f32_16x16x32_bf16(ah, bl, acc1, 0,0,0);
    }
    acc1 = __builtin_amdgcn_mfma_f32_16x16x32_bf16(ah, bh, acc1, 0,0,0);

    load_frag<F32>(x, baseB2 + o, bh, bl);
    if (F32) {
      acc2 = __builtin_amdgcn_mfma_f32_16x16x32_bf16(al, bh, acc2, 0,0,0);
      acc2 = __builtin_amdgcn_mfma_f32_16x16x32_bf16(ah, bl, acc2, 0,0,0);
    }
    acc2 = __builtin_amdgcn_mfma_f32_16x16x32_bf16(ah, bh, acc2, 0,0,0);
  }

  int gi_base = it * 16 + q * 4;
  floatx4 accs[3] = {acc0, acc1, acc2};
#pragma unroll
  for (int u = 0; u < 3; ++u) {
    int col = jg * 48 + u * 16 + m;
    float rn = (float)rnormd[b * NB + col];
#pragma unroll
    for (int r = 0; r < 4; ++r) {
      int gi = gi_base + r;
      if (gi <= 288)
        S[((size_t)b * NA + gi) * NB + col] = accs[u][r] * rn;
    }
  }
}
__global__ __launch_bounds__(256) void k_scores(const void* __restrict__ x,
                                                const double* __restrict__ rnormd,
                                                float* __restrict__ S,
                                                const unsigned int* __restrict__ flag) {
  if (*flag) scores_body<1>(x, rnormd, S); else scores_body<0>(x, rnormd, S);
}

// ---------------------------------------------------------------------------
// Stage 2: per row i (wave): find stored max, recheck all cols within eps in
// exact f64 (ascending col, strict > => numpy first-index tie-break).
// ---------------------------------------------------------------------------
template<int F32>
__device__ __forceinline__ void argmax_body(const void* x, const double* rnormd,
                                            const float* S, int* dst) {
  int wid = threadIdx.x >> 6, lane = threadIdx.x & 63;
  int gw = blockIdx.x * 4 + wid;           // grid = B*NB/4
  int b = gw / NB, i = gw - b * NB + 1;    // i in [1,288]
  const float* Srow = S + ((size_t)b * NA + i) * NB;

  float sv[5]; float mx = -1e30f;
#pragma unroll
  for (int g = 0; g < 5; ++g) {
    int c = g * 64 + lane;
    sv[g] = (c < NB) ? Srow[c] : -1e30f;
    mx = fmaxf(mx, sv[g]);
  }
#pragma unroll
  for (int d = 32; d >= 1; d >>= 1) mx = fmaxf(mx, __shfl_xor(mx, d, 64));
  float thr = mx - EPS_MARGIN;

  float av[16];
  load16<F32>(x, (size_t)(b * T_ + 2 * i) * C_ + lane * 16, av);

  double best = -1e300; int bestc = 0;
  for (int g = 0; g < 5; ++g) {
    unsigned long long mask = __ballot(sv[g] >= thr);
    while (mask) {
      int c = __ffsll((long long)mask) - 1;
      mask &= mask - 1;
      int col = g * 64 + c;
      float bv[16];
      load16<F32>(x, (size_t)(b * T_ + 2 * col + 1) * C_ + lane * 16, bv);
      double s = 0.0;
#pragma unroll
      for (int t = 0; t < 16; ++t) s += (double)av[t] * (double)bv[t];
#pragma unroll
      for (int d = 32; d >= 1; d >>= 1) s += __shfl_xor(s, d, 64);
      s *= rnormd[b * NB + col];
      if (s > best) { best = s; bestc = col; }
    }
  }
  if (lane == 0) dst[b * NA + i] = bestc;
}
__global__ __launch_bounds__(256) void k_argmax(const void* __restrict__ x,
                                                const double* __restrict__ rnormd,
                                                const float* __restrict__ S,
                                                int* __restrict__ dst,
                                                const unsigned int* __restrict__ flag) {
  if (*flag) argmax_body<1>(x, rnormd, S, dst); else argmax_body<0>(x, rnormd, S, dst);
}

// ---------------------------------------------------------------------------
// Merge: out[b][0] = x[b][0]; out[b][1+j] = mean(odd 2j+1, evens with dst==j)
// ---------------------------------------------------------------------------
template<int F32>
__device__ __forceinline__ void merge_body(const void* x, const int* dst, void* out) {
  __shared__ int dstv[NA];
  int b = blockIdx.y, tid = threadIdx.x;
  for (int i = tid; i < NA; i += 256) dstv[i] = (i >= 1) ? dst[b * NA + i] : -1;
  __syncthreads();

  int wid = tid >> 6, lane = tid & 63;
  int orow = blockIdx.x * 4 + wid;
  if (orow >= NA) return;

  const size_t xb = (size_t)b * T_ * C_;
  int c0 = lane * 16;
  float acc[16];
  float inv = 1.0f;

  if (orow == 0) {
    load16<F32>(x, xb + c0, acc);
  } else {
    int j = orow - 1;
    load16<F32>(x, xb + (size_t)(2 * j + 1) * C_ + c0, acc);
    int cnt = 1;
    for (int i = 1; i <= 288; ++i) {
      if (dstv[i] == j) {
        cnt++;
        float tv[16];
        load16<F32>(x, xb + (size_t)(2 * i) * C_ + c0, tv);
#pragma unroll
        for (int t = 0; t < 16; ++t) acc[t] += tv[t];
      }
    }
    inv = 1.0f / (float)cnt;
  }
#pragma unroll
  for (int t = 0; t < 16; ++t) acc[t] *= inv;
  store16<F32>(out, ((size_t)b * NA + orow) * C_ + c0, acc);
}
__global__ __launch_bounds__(256) void k_merge(const void* __restrict__ x,
                                               const int* __restrict__ dst,
                                               void* __restrict__ out,
                                               const unsigned int* __restrict__ flag) {
  if (*flag) merge_body<1>(x, dst, out); else merge_body<0>(x, dst, out);
}

// ---------------------------------------------------------------------------
extern "C" void kernel_launch(void* const* d_in, const int* in_sizes, int n_in,
                              void* d_out, int out_size, void* d_ws, size_t ws_size,
                              hipStream_t stream) {
  const void* x = d_in[0];
  char* ws = (char*)d_ws;
  unsigned int* flag = (unsigned int*)(ws + FLAG_OFF);
  double* rnormd     = (double*)(ws + RNORM_OFF);
  int* dst           = (int*)(ws + DST_OFF);
  float* S           = (float*)(ws + S_OFF);     // ~21.3 MB

  k_detect<<<1, 64, 0, stream>>>((const unsigned short*)x, flag);
  k_norms <<<B_ * NB / 4, 256, 0, stream>>>(x, rnormd, flag);
  k_scores<<<B_ * 19 * 6 / 4, 256, 0, stream>>>(x, rnormd, S, flag);
  k_argmax<<<B_ * NB / 4, 256, 0, stream>>>(x, rnormd, S, dst, flag);
  k_merge <<<dim3((NA + 3) / 4, B_), 256, 0, stream>>>(x, dst, d_out, flag);
}

// Round 4
// 353.823 us; speedup vs baseline: 1.4585x; 1.4585x over previous
//
#include <hip/hip_runtime.h>
#include <hip/hip_bf16.h>
#include <math.h>

// ToMe merge, B=64 T=577 C=1024. WORLD (established round 3): input f32,
// output f32 (comparison done at bf16 granularity by the harness; values
// likely bf16-quantized upstream). Evidence: R1 kernel with runtime dtype
// detector PASSED, semantically-equivalent pure-bf16 kernels (R0, R2) both
// FAILED with identical absmax 6.97 => detector took the f32 path.
//
// r=288 => unm = {token 0}; out row 0 = token 0; out row 1+j = mean(odd token
// 2j+1, all even tokens i>=1 with argmax_j cos(a_i,b_j) == j), first-index
// tie-break. Exactness: stage-1 scores via truncated-bf16 MFMA (error sigma
// ~0.004 on normalized scale, gaps ~0.4) -> S; stage-2 rechecks every col
// within EPS=0.08 (~20 sigma) of row max with exact f64 dot on the raw f32
// data (ascending col, strict '>' => numpy first-index semantics).

#define B_   64
#define T_   577
#define C_   1024
#define NA   289
#define NB   288

#define EPS_MARGIN 0.08f

#define BOFF 16384              // B-tile LDS byte offset (A = 128 rows * 128 B)

typedef __bf16 bf16x8 __attribute__((ext_vector_type(8)));
typedef float  floatx4 __attribute__((ext_vector_type(4)));

// pack two f32 (lo=elem0, hi=elem1) -> two truncated bf16 in one dword.
// perm sel 0x07060302: bytes [a.b3 a.b2 b.b3 b.b2] = (a&0xFFFF0000)|(b>>16)
__device__ __forceinline__ unsigned int pk_bf16_trunc(unsigned int e1, unsigned int e0) {
  return __builtin_amdgcn_perm(e1, e0, 0x07060302u);
}

// load 16 consecutive f32 elems (per-lane) into v[16]
__device__ __forceinline__ void load16f(const float* x, size_t off, float* v) {
  const float4* p = (const float4*)(x + off);
  float4 a = p[0], b = p[1], c = p[2], d = p[3];
  v[0]=a.x; v[1]=a.y; v[2]=a.z; v[3]=a.w;
  v[4]=b.x; v[5]=b.y; v[6]=b.z; v[7]=b.w;
  v[8]=c.x; v[9]=c.y; v[10]=c.z; v[11]=c.w;
  v[12]=d.x; v[13]=d.y; v[14]=d.z; v[15]=d.w;
}

// ws layout (bytes)
#define RNORMD_OFF 0                      // double[B_*NB]   147456
#define RNORMF_OFF 147456                 // float[B_*NB]     73728
#define DST_OFF    221184                 // int[B_*NA]       73984
#define S_OFF      295168                 // float[B_*NA*NB] ~21.3 MB

// ---------------------------------------------------------------------------
// rnorm[b][j] = 1/||x[b,2j+1,:]|| ; f64 for exact recheck, f32 for S scaling
// ---------------------------------------------------------------------------
__global__ __launch_bounds__(256) void k_norms(const float* __restrict__ x,
                                               double* __restrict__ rnormd,
                                               float* __restrict__ rnormf) {
  int wid = threadIdx.x >> 6, lane = threadIdx.x & 63;
  int gw = blockIdx.x * 4 + wid;           // grid = B*NB/4 exactly
  int b = gw / NB, j = gw - b * NB;
  float v[16];
  load16f(x, (size_t)(b * T_ + 2 * j + 1) * C_ + lane * 16, v);
  double s = 0.0;
#pragma unroll
  for (int t = 0; t < 16; ++t) s += (double)v[t] * (double)v[t];
#pragma unroll
  for (int d = 32; d >= 1; d >>= 1) s += __shfl_xor(s, d, 64);
  if (lane == 0) {
    double r = 1.0 / sqrt(s);
    rnormd[b * NB + j] = r;
    rnormf[b * NB + j] = (float)r;
  }
}

// ---------------------------------------------------------------------------
// S[b][i][j] = dot(a_i, b_j) * rnorm_j, LDS-tiled MFMA GEMM, f32 input
// truncated to bf16 at staging (1 v_perm per pair). Block: (b=bx, tile=by):
// rb = by>>1 (rows rb*128..+127, even tokens, clamped), cb = by&1 (cols
// cb*144..+143, odd tokens). BK=64. XOR swizzle: physical slot s of row r
// holds global k-granule s^(r&7) (granule = 8 elems = 16 B) -> frag
// ds_read_b128 spreads all 8 bank-groups. Grid (64, 6): a batch's 6 blocks
// share linear%8 -> same XCD -> L2-served re-reads (2.3 MB/batch < 4 MB L2).
// A/B frag: row/col = lane&15, k = (lane>>4)*8+e. C/D: col=lane&15,
// row=(lane>>4)*4+reg  [m89/m91].
// ---------------------------------------------------------------------------
__global__ __launch_bounds__(256, 2) void k_scores(const float* __restrict__ x,
                                                   const float* __restrict__ rnormf,
                                                   float* __restrict__ S) {
  __shared__ unsigned char smem[16384 + 18432];   // A 128x128B, B 144x128B
  int tid = threadIdx.x;
  int b  = blockIdx.x;
  int rb = blockIdx.y >> 1;                 // 0..2
  int cb = blockIdx.y & 1;                  // 0..1
  int wv = tid >> 6, lane = tid & 63;
  int m = lane & 15, q = lane >> 4;
  int sw = m & 7;

  floatx4 acc0[9], acc1[9];
#pragma unroll
  for (int j = 0; j < 9; ++j) { acc0[j] = (floatx4){0,0,0,0}; acc1[j] = (floatx4){0,0,0,0}; }

  const int r0 = wv * 32 + m;               // A row of i-tile 2*wv
  const int r1 = r0 + 16;                   // i-tile 2*wv+1

  for (int kc = 0; kc < 16; ++kc) {
    int k0 = kc * 64;
    __syncthreads();
    // stage A (128 rows) + B (144 rows), 8 granules/row, f32->bf16 truncate
    for (int v = tid; v < 2176; v += 256) {
      int isB  = v >= 1024;
      int w    = isB ? v - 1024 : v;
      int row  = w >> 3, slot = w & 7;
      int gk   = slot ^ (row & 7);
      int tok;
      if (isB) tok = 2 * (cb * 144 + row) + 1;
      else { tok = 2 * (rb * 128 + row); if (tok > 576) tok = 576; }
      const uint4* src = (const uint4*)(x + (size_t)(b * T_ + tok) * C_ + k0 + gk * 8);
      uint4 lo = src[0], hi = src[1];       // 8 f32
      uint4 o;
      o.x = pk_bf16_trunc(lo.y, lo.x);
      o.y = pk_bf16_trunc(lo.w, lo.z);
      o.z = pk_bf16_trunc(hi.y, hi.x);
      o.w = pk_bf16_trunc(hi.w, hi.z);
      *(uint4*)(smem + (isB ? BOFF : 0) + row * 128 + slot * 16) = o;
    }
    __syncthreads();
#pragma unroll
    for (int s = 0; s < 2; ++s) {
      int slot = (s * 4 + q) ^ sw;
      bf16x8 a0 = *(const bf16x8*)(smem + r0 * 128 + slot * 16);
      bf16x8 a1 = *(const bf16x8*)(smem + r1 * 128 + slot * 16);
#pragma unroll
      for (int j = 0; j < 9; ++j) {
        bf16x8 bfrag = *(const bf16x8*)(smem + BOFF + (j * 16 + m) * 128 + slot * 16);
        acc0[j] = __builtin_amdgcn_mfma_f32_16x16x32_bf16(a0, bfrag, acc0[j], 0,0,0);
        acc1[j] = __builtin_amdgcn_mfma_f32_16x16x32_bf16(a1, bfrag, acc1[j], 0,0,0);
      }
    }
  }

  int gi_base = rb * 128 + wv * 32 + q * 4;
#pragma unroll
  for (int j = 0; j < 9; ++j) {
    int col = cb * 144 + j * 16 + m;
    float rn = rnormf[b * NB + col];
#pragma unroll
    for (int r = 0; r < 4; ++r) {
      int gi0 = gi_base + r;
      if (gi0 < NA) S[((size_t)b * NA + gi0) * NB + col] = acc0[j][r] * rn;
      int gi1 = gi0 + 16;
      if (gi1 < NA) S[((size_t)b * NA + gi1) * NB + col] = acc1[j][r] * rn;
    }
  }
}

// ---------------------------------------------------------------------------
// Per row i: stored f32 max, then exact f64 recheck of cols within EPS
// (ascending col, strict > => numpy first-index tie-break).
// ---------------------------------------------------------------------------
__global__ __launch_bounds__(256) void k_argmax(const float* __restrict__ x,
                                                const double* __restrict__ rnormd,
                                                const float* __restrict__ S,
                                                int* __restrict__ dst) {
  int wid = threadIdx.x >> 6, lane = threadIdx.x & 63;
  int gw = blockIdx.x * 4 + wid;           // grid = B*NB/4
  int b = gw / NB, i = gw - b * NB + 1;    // i in [1,288]
  const float* Srow = S + ((size_t)b * NA + i) * NB;

  float sv[5]; float mx = -1e30f;
#pragma unroll
  for (int g = 0; g < 5; ++g) {
    int c = g * 64 + lane;
    sv[g] = (c < NB) ? Srow[c] : -1e30f;
    mx = fmaxf(mx, sv[g]);
  }
#pragma unroll
  for (int d = 32; d >= 1; d >>= 1) mx = fmaxf(mx, __shfl_xor(mx, d, 64));
  float thr = mx - EPS_MARGIN;

  float av[16];
  load16f(x, (size_t)(b * T_ + 2 * i) * C_ + lane * 16, av);

  double best = -1e300; int bestc = 0;
  for (int g = 0; g < 5; ++g) {
    unsigned long long mask = __ballot(sv[g] >= thr);
    while (mask) {
      int c = __ffsll((long long)mask) - 1;
      mask &= mask - 1;
      int col = g * 64 + c;
      float bv[16];
      load16f(x, (size_t)(b * T_ + 2 * col + 1) * C_ + lane * 16, bv);
      double s = 0.0;
#pragma unroll
      for (int t = 0; t < 16; ++t) s += (double)av[t] * (double)bv[t];
#pragma unroll
      for (int d = 32; d >= 1; d >>= 1) s += __shfl_xor(s, d, 64);
      s *= rnormd[b * NB + col];
      if (s > best) { best = s; bestc = col; }
    }
  }
  if (lane == 0) dst[b * NA + i] = bestc;
}

// ---------------------------------------------------------------------------
// Merge. Cooperative membership scan builds per-output-row index lists in
// LDS, then each wave gathers its list. out[b][0] = x[b][0];
// out[b][1+j] = mean(odd 2j+1, evens i with dst[i]==j).
// ---------------------------------------------------------------------------
__global__ __launch_bounds__(256) void k_merge(const float* __restrict__ x,
                                               const int* __restrict__ dst,
                                               float* __restrict__ out) {
  __shared__ int dstv[NA];
  __shared__ unsigned short lists[4][292];
  __shared__ int cnts[4];
  int b = blockIdx.y, tid = threadIdx.x;
  int orow_base = blockIdx.x * 4;

  for (int i = tid; i < NA; i += 256) dstv[i] = (i >= 1) ? dst[b * NA + i] : -1;
  if (tid < 4) cnts[tid] = 0;
  __syncthreads();

  for (int i = 1 + tid; i <= 288; i += 256) {
    int d = dstv[i];
#pragma unroll
    for (int w4 = 0; w4 < 4; ++w4) {
      int orow_w = orow_base + w4;
      if (orow_w >= 1 && orow_w < NA && d == orow_w - 1) {
        int idx = atomicAdd(&cnts[w4], 1);
        lists[w4][idx] = (unsigned short)i;
      }
    }
  }
  __syncthreads();

  int wv = tid >> 6, lane = tid & 63;
  int orow = orow_base + wv;
  if (orow >= NA) return;

  const size_t xb = (size_t)b * T_ * C_;
  int c0 = lane * 16;
  float acc[16];
  float inv = 1.0f;

  if (orow == 0) {
    load16f(x, xb + c0, acc);
  } else {
    int j = orow - 1;
    load16f(x, xb + (size_t)(2 * j + 1) * C_ + c0, acc);
    int cnt = cnts[wv];
    for (int e = 0; e < cnt; ++e) {
      int i = lists[wv][e];
      float tv[16];
      load16f(x, xb + (size_t)(2 * i) * C_ + c0, tv);
#pragma unroll
      for (int t = 0; t < 16; ++t) acc[t] += tv[t];
    }
    inv = 1.0f / (float)(cnt + 1);
  }

  float4* op = (float4*)(out + ((size_t)b * NA + orow) * C_ + c0);
  op[0] = make_float4(acc[0]*inv,  acc[1]*inv,  acc[2]*inv,  acc[3]*inv);
  op[1] = make_float4(acc[4]*inv,  acc[5]*inv,  acc[6]*inv,  acc[7]*inv);
  op[2] = make_float4(acc[8]*inv,  acc[9]*inv,  acc[10]*inv, acc[11]*inv);
  op[3] = make_float4(acc[12]*inv, acc[13]*inv, acc[14]*inv, acc[15]*inv);
}

// ---------------------------------------------------------------------------
extern "C" void kernel_launch(void* const* d_in, const int* in_sizes, int n_in,
                              void* d_out, int out_size, void* d_ws, size_t ws_size,
                              hipStream_t stream) {
  const float* x = (const float*)d_in[0];
  float* out     = (float*)d_out;
  char* ws = (char*)d_ws;
  double* rnormd = (double*)(ws + RNORMD_OFF);
  float*  rnormf = (float*)(ws + RNORMF_OFF);
  int*    dst    = (int*)(ws + DST_OFF);
  float*  S      = (float*)(ws + S_OFF);

  k_norms <<<B_ * NB / 4, 256, 0, stream>>>(x, rnormd, rnormf);
  k_scores<<<dim3(B_, 6), 256, 0, stream>>>(x, rnormf, S);
  k_argmax<<<B_ * NB / 4, 256, 0, stream>>>(x, rnormd, S, dst);
  k_merge <<<dim3((NA + 3) / 4, B_), 256, 0, stream>>>(x, dst, out);
}

// Round 5
// 341.485 us; speedup vs baseline: 1.5112x; 1.0361x over previous
//
#include <hip/hip_runtime.h>
#include <math.h>

// ToMe merge, B=64 T=577 C=1024, f32 in / f32 out (world established R3/R4).
// r=288 => unm={token 0}; out[b][0]=x[b][0]; out[b][1+j] = mean(odd token
// 2j+1, evens i>=1 with argmax_j cos(a_i,b_j)==j), numpy first-index ties.
//
// R5 structure: no S matrix. k_scores (96x96 tiles, grid 768) computes
// truncated-bf16 MFMA scores, reduces per-row argmax per 48-col group
// in-register, writes group-winner u64 + rare extras (within EPS of group
// max). k_recheck combines 6 group winners per row; if >1 candidate within
// EPS of global stage-1 max, exact f64 re-dot decides (ascending-col strict
// tie-break). Guarantee: exact winner t has S1(t) >= gm - 2E; EPS=0.04 >> 2E
// (R4 passed with same truncation arithmetic at EPS=0.08).

#define B_   64
#define T_   577
#define C_   1024
#define NA   289
#define NB   288
#define EPS_MARGIN 0.04f

#define RPAD 384                 // 4 row-tiles x 96
#define EXTRA_CAP 12

typedef __bf16 bf16x8 __attribute__((ext_vector_type(8)));
typedef float  floatx4 __attribute__((ext_vector_type(4)));
typedef unsigned long long u64;

// ws layout (bytes)
#define ECNT_OFF   0                                  // u32[64*384]   98304
#define GRPWIN_OFF 98304                              // u64[64*384*6] 1179648
#define EXTRA_OFF  (GRPWIN_OFF + 1179648)             // u64[64*384*12] 2359296
#define DST_OFF    (EXTRA_OFF + 2359296)              // int[64*NA]

__device__ __forceinline__ u64 shfl_xor_u64(u64 v, int msk) {
  unsigned int lo = (unsigned int)v, hi = (unsigned int)(v >> 32);
  lo = __shfl_xor(lo, msk, 64);
  hi = __shfl_xor(hi, msk, 64);
  return ((u64)hi << 32) | (u64)lo;
}
__device__ __forceinline__ double shfl_xor_f64(double v, int msk) {
  u64 u = __double_as_longlong(v);
  return __longlong_as_double((long long)shfl_xor_u64(u, msk));
}

// orderable f32 key
__device__ __forceinline__ unsigned int fkey(float s) {
  unsigned int fb = __float_as_uint(s);
  return (fb & 0x80000000u) ? ~fb : (fb | 0x80000000u);
}
__device__ __forceinline__ float keyf(unsigned int k) {
  return (k & 0x80000000u) ? __uint_as_float(k ^ 0x80000000u) : __uint_as_float(~k);
}
__device__ __forceinline__ u64 packsc(float s, int col) {
  return ((u64)fkey(s) << 32) | (u64)(0xFFFFFFFFu - (unsigned int)col);
}
__device__ __forceinline__ int pcol(u64 p) {
  return (int)(0xFFFFFFFFu - (unsigned int)(p & 0xFFFFFFFFull));
}
__device__ __forceinline__ float pscore(u64 p) { return keyf((unsigned int)(p >> 32)); }

// two f32 -> two truncated bf16 packed in one dword
__device__ __forceinline__ unsigned int pk_bf16_trunc(unsigned int e1, unsigned int e0) {
  return __builtin_amdgcn_perm(e1, e0, 0x07060302u);
}

__device__ __forceinline__ void load16f(const float* x, size_t off, float* v) {
  const float4* p = (const float4*)(x + off);
  float4 a = p[0], b = p[1], c = p[2], d = p[3];
  v[0]=a.x; v[1]=a.y; v[2]=a.z; v[3]=a.w;
  v[4]=b.x; v[5]=b.y; v[6]=b.z; v[7]=b.w;
  v[8]=c.x; v[9]=c.y; v[10]=c.z; v[11]=c.w;
  v[12]=d.x; v[13]=d.y; v[14]=d.z; v[15]=d.w;
}

// ---------------------------------------------------------------------------
// k_scores: grid (64 batches, 4 row-tiles, 3 col-tiles), 256 thr, LDS 24 KB.
// Tile 96 rows (even tokens, clamped past 288) x 96 cols (odd tokens). BK=64.
// XOR swizzle: physical slot s of LDS row r holds k-granule s^(r&7)
// (granule = 8 bf16 = 16 B) -> conflict-free ds_read_b128 (R4: 0 conflicts).
// Wave w: i-tiles (w>>1)*3..+2, j-tiles (w&1)*3..+2 (9 accs).
// B-staging accumulates per-col sumsq in LDS (fold of old k_norms).
// Epilogue: per-row quad reduce -> group winner u64 + extras.
// A/B frag: row/col = lane&15, k=(lane>>4)*8+e. C/D: col=lane&15,
// row=(lane>>4)*4+reg  [m89/m91].
// ---------------------------------------------------------------------------
__global__ __launch_bounds__(256, 2) void k_scores(const float* __restrict__ x,
                                                   u64* __restrict__ grpwin,
                                                   unsigned int* __restrict__ ecnt,
                                                   u64* __restrict__ extras) {
  __shared__ unsigned char smem[24576];     // A 96x128B @0, B 96x128B @12288
  __shared__ float sumsq[96];
  int tid = threadIdx.x;
  int b  = blockIdx.x;
  int rt = blockIdx.y;                      // 0..3
  int ct = blockIdx.z;                      // 0..2
  int wv = tid >> 6, lane = tid & 63;
  int m = lane & 15, q = lane >> 4;
  int sw = m & 7;

  if (tid < 96) sumsq[tid] = 0.f;

  floatx4 acc[3][3];
#pragma unroll
  for (int ii = 0; ii < 3; ++ii)
#pragma unroll
    for (int jj = 0; jj < 3; ++jj) acc[ii][jj] = (floatx4){0,0,0,0};

  const int ib = (wv >> 1) * 3;             // i-tile base
  const int jb = (wv & 1) * 3;              // j-tile base

  for (int kc = 0; kc < 16; ++kc) {
    int k0 = kc * 64;
    __syncthreads();
    // stage A (96 rows) + B (96 rows), 8 granules/row, f32 -> trunc bf16
    for (int v = tid; v < 1536; v += 256) {
      int isB  = v >= 768;
      int w    = isB ? v - 768 : v;
      int row  = w >> 3, slot = w & 7;
      int gk   = slot ^ (row & 7);
      int tok;
      if (isB) tok = 2 * (ct * 96 + row) + 1;
      else { tok = 2 * (rt * 96 + row); if (tok > 576) tok = 576; }
      const uint4* src = (const uint4*)(x + (size_t)(b * T_ + tok) * C_ + k0 + gk * 8);
      uint4 lo = src[0], hi = src[1];
      uint4 o;
      o.x = pk_bf16_trunc(lo.y, lo.x);
      o.y = pk_bf16_trunc(lo.w, lo.z);
      o.z = pk_bf16_trunc(hi.y, hi.x);
      o.w = pk_bf16_trunc(hi.w, hi.z);
      *(uint4*)(smem + (isB ? 12288 : 0) + row * 128 + slot * 16) = o;
      if (isB) {
        float f0 = __uint_as_float(lo.x), f1 = __uint_as_float(lo.y);
        float f2 = __uint_as_float(lo.z), f3 = __uint_as_float(lo.w);
        float f4 = __uint_as_float(hi.x), f5 = __uint_as_float(hi.y);
        float f6 = __uint_as_float(hi.z), f7 = __uint_as_float(hi.w);
        float ss = f0*f0 + f1*f1 + f2*f2 + f3*f3 + f4*f4 + f5*f5 + f6*f6 + f7*f7;
        atomicAdd(&sumsq[row], ss);
      }
    }
    __syncthreads();
#pragma unroll
    for (int s = 0; s < 2; ++s) {
      int slot = (s * 4 + q) ^ sw;
      bf16x8 af[3], bf[3];
#pragma unroll
      for (int ii = 0; ii < 3; ++ii)
        af[ii] = *(const bf16x8*)(smem + ((ib + ii) * 16 + m) * 128 + slot * 16);
#pragma unroll
      for (int jj = 0; jj < 3; ++jj)
        bf[jj] = *(const bf16x8*)(smem + 12288 + ((jb + jj) * 16 + m) * 128 + slot * 16);
#pragma unroll
      for (int ii = 0; ii < 3; ++ii)
#pragma unroll
        for (int jj = 0; jj < 3; ++jj)
          acc[ii][jj] = __builtin_amdgcn_mfma_f32_16x16x32_bf16(af[ii], bf[jj], acc[ii][jj], 0,0,0);
    }
  }

  // epilogue: normalize, per-row argmax within this wave's 48 cols
  float rn[3];
#pragma unroll
  for (int jj = 0; jj < 3; ++jj) rn[jj] = rsqrtf(sumsq[(jb + jj) * 16 + m]);

  int g = ct * 2 + (wv & 1);                // col-group id 0..5
#pragma unroll
  for (int ii = 0; ii < 3; ++ii) {
#pragma unroll
    for (int r = 0; r < 4; ++r) {
      u64 pj[3];
#pragma unroll
      for (int jj = 0; jj < 3; ++jj) {
        float s = acc[ii][jj][r] * rn[jj];
        pj[jj] = packsc(s, ct * 96 + (jb + jj) * 16 + m);
      }
      u64 pk = pj[0];
      if (pj[1] > pk) pk = pj[1];
      if (pj[2] > pk) pk = pj[2];
#pragma unroll
      for (int d = 1; d < 16; d <<= 1) {
        u64 o = shfl_xor_u64(pk, d);
        if (o > pk) pk = o;
      }
      int grow = rt * 96 + (ib + ii) * 16 + q * 4 + r;
      float thr = pscore(pk) - EPS_MARGIN;
      size_t rbase = (size_t)b * RPAD + grow;
#pragma unroll
      for (int jj = 0; jj < 3; ++jj) {
        if (pj[jj] != pk && pscore(pj[jj]) >= thr) {
          unsigned int idx = atomicAdd(&ecnt[rbase], 1u);
          if (idx < EXTRA_CAP) extras[rbase * EXTRA_CAP + idx] = pj[jj];
        }
      }
      if (m == 0) grpwin[rbase * 6 + g] = pk;
    }
  }
}

// ---------------------------------------------------------------------------
// k_recheck: wave per row i in [1,288]. Stage-1 global max over 6 group
// winners; candidates = winners+extras within EPS. 1 candidate -> done.
// Else exact f64 dot / ||b|| per candidate (tie -> lowest col).
// ---------------------------------------------------------------------------
__global__ __launch_bounds__(256) void k_recheck(const float* __restrict__ x,
                                                 const u64* __restrict__ grpwin,
                                                 const unsigned int* __restrict__ ecnt,
                                                 const u64* __restrict__ extras,
                                                 int* __restrict__ dst) {
  int wid = threadIdx.x >> 6, lane = threadIdx.x & 63;
  int gw = blockIdx.x * 4 + wid;            // grid = B*NB/4
  int b = gw / NB, i = gw - b * NB + 1;     // i in [1,288]
  size_t rbase = (size_t)b * RPAD + i;

  u64 v = (lane < 6) ? grpwin[rbase * 6 + lane] : 0ull;
#pragma unroll
  for (int d = 1; d < 8; d <<= 1) {
    u64 o = shfl_xor_u64(v, d);
    if (o > v) v = o;
  }
  // lanes 0..7 now agree; broadcast to all via one more sweep
  v = shfl_xor_u64(v, 0) , v = v;           // no-op keep
  {
    unsigned int lo = (unsigned int)v, hi = (unsigned int)(v >> 32);
    lo = __shfl(lo, 0, 64); hi = __shfl(hi, 0, 64);
    v = ((u64)hi << 32) | lo;
  }
  float thr = pscore(v) - EPS_MARGIN;

  u64 cand[14]; int nc = 0;
#pragma unroll
  for (int t = 0; t < 6; ++t) {
    u64 w = grpwin[rbase * 6 + t];
    if (pscore(w) >= thr && nc < 14) cand[nc++] = w;
  }
  unsigned int ec = ecnt[rbase]; if (ec > EXTRA_CAP) ec = EXTRA_CAP;
  for (unsigned int t = 0; t < ec; ++t) {
    u64 w = extras[rbase * EXTRA_CAP + t];
    if (pscore(w) >= thr && nc < 14) cand[nc++] = w;
  }

  int best;
  if (nc <= 1) {
    best = pcol(v);
  } else {
    float av[16];
    load16f(x, (size_t)(b * T_ + 2 * i) * C_ + lane * 16, av);
    double bs = -1e300; int bc = 1 << 30;
    for (int c = 0; c < nc; ++c) {
      int col = pcol(cand[c]);
      float bv[16];
      load16f(x, (size_t)(b * T_ + 2 * col + 1) * C_ + lane * 16, bv);
      double dot = 0.0, nsq = 0.0;
#pragma unroll
      for (int t = 0; t < 16; ++t) {
        dot += (double)av[t] * (double)bv[t];
        nsq += (double)bv[t] * (double)bv[t];
      }
#pragma unroll
      for (int d = 32; d >= 1; d >>= 1) {
        dot += shfl_xor_f64(dot, d);
        nsq += shfl_xor_f64(nsq, d);
      }
      double s = dot / sqrt(nsq);
      if (s > bs || (s == bs && col < bc)) { bs = s; bc = col; }
    }
    best = bc;
  }
  if (lane == 0) dst[b * NA + i] = best;
}

// ---------------------------------------------------------------------------
// k_merge: membership lists in LDS, wave per output row.
// ---------------------------------------------------------------------------
__global__ __launch_bounds__(256) void k_merge(const float* __restrict__ x,
                                               const int* __restrict__ dst,
                                               float* __restrict__ out) {
  __shared__ int dstv[NA];
  __shared__ unsigned short lists[4][292];
  __shared__ int cnts[4];
  int b = blockIdx.y, tid = threadIdx.x;
  int orow_base = blockIdx.x * 4;

  for (int i = tid; i < NA; i += 256) dstv[i] = (i >= 1) ? dst[b * NA + i] : -1;
  if (tid < 4) cnts[tid] = 0;
  __syncthreads();

  for (int i = 1 + tid; i <= 288; i += 256) {
    int d = dstv[i];
#pragma unroll
    for (int w4 = 0; w4 < 4; ++w4) {
      int orow_w = orow_base + w4;
      if (orow_w >= 1 && orow_w < NA && d == orow_w - 1) {
        int idx = atomicAdd(&cnts[w4], 1);
        lists[w4][idx] = (unsigned short)i;
      }
    }
  }
  __syncthreads();

  int wv = tid >> 6, lane = tid & 63;
  int orow = orow_base + wv;
  if (orow >= NA) return;

  const size_t xb = (size_t)b * T_ * C_;
  int c0 = lane * 16;
  float acc[16];
  float inv = 1.0f;

  if (orow == 0) {
    load16f(x, xb + c0, acc);
  } else {
    int j = orow - 1;
    load16f(x, xb + (size_t)(2 * j + 1) * C_ + c0, acc);
    int cnt = cnts[wv];
    for (int e = 0; e < cnt; ++e) {
      int i = lists[wv][e];
      float tv[16];
      load16f(x, xb + (size_t)(2 * i) * C_ + c0, tv);
#pragma unroll
      for (int t = 0; t < 16; ++t) acc[t] += tv[t];
    }
    inv = 1.0f / (float)(cnt + 1);
  }

  float4* op = (float4*)(out + ((size_t)b * NA + orow) * C_ + c0);
  op[0] = make_float4(acc[0]*inv,  acc[1]*inv,  acc[2]*inv,  acc[3]*inv);
  op[1] = make_float4(acc[4]*inv,  acc[5]*inv,  acc[6]*inv,  acc[7]*inv);
  op[2] = make_float4(acc[8]*inv,  acc[9]*inv,  acc[10]*inv, acc[11]*inv);
  op[3] = make_float4(acc[12]*inv, acc[13]*inv, acc[14]*inv, acc[15]*inv);
}

// ---------------------------------------------------------------------------
extern "C" void kernel_launch(void* const* d_in, const int* in_sizes, int n_in,
                              void* d_out, int out_size, void* d_ws, size_t ws_size,
                              hipStream_t stream) {
  const float* x = (const float*)d_in[0];
  float* out     = (float*)d_out;
  char* ws = (char*)d_ws;
  unsigned int* ecnt = (unsigned int*)(ws + ECNT_OFF);
  u64* grpwin        = (u64*)(ws + GRPWIN_OFF);
  u64* extras        = (u64*)(ws + EXTRA_OFF);
  int* dst           = (int*)(ws + DST_OFF);

  hipMemsetAsync(ecnt, 0, (size_t)B_ * RPAD * sizeof(unsigned int), stream);
  k_scores <<<dim3(B_, 4, 3), 256, 0, stream>>>(x, grpwin, ecnt, extras);
  k_recheck<<<B_ * NB / 4, 256, 0, stream>>>(x, grpwin, ecnt, extras, dst);
  k_merge  <<<dim3((NA + 3) / 4, B_), 256, 0, stream>>>(x, dst, out);
}

// Round 6
// 309.106 us; speedup vs baseline: 1.6695x; 1.1048x over previous
//
#include <hip/hip_runtime.h>
#include <math.h>

// ToMe merge, B=64 T=577 C=1024, f32 in / f32 out (world established R3/R4).
// r=288 => unm={token 0}; out[b][0]=x[b][0]; out[b][1+j] = mean(odd token
// 2j+1, evens i>=1 with argmax_j cos(a_i,b_j)==j), numpy first-index ties.
//
// R6: k_scores software-pipelined: LDS double-buffer (2x24.5KB), ONE barrier
// per chunk; chunk k+1 global loads issue before chunk k MFMA phase and land
// during it (R5 was barrier->stage->barrier->compute: latency fully exposed
// 16x/block -> 127us at 4.4% MfmaUtil). In-loop LDS atomics for sumsq
// replaced by per-thread register partials (each thread's 3 B-rows are fixed
// across chunks) + 3 epilogue atomics.
// Candidate scheme unchanged (R5, passed): per-row 48-col group winner u64 +
// extras within EPS of group max; k_recheck resolves with exact f64 when >1
// candidate within EPS of global stage-1 max. EPS=0.04 >> truncation error.

#define B_   64
#define T_   577
#define C_   1024
#define NA   289
#define NB   288
#define EPS_MARGIN 0.04f

#define RPAD 384                 // 4 row-tiles x 96
#define EXTRA_CAP 12

typedef __bf16 bf16x8 __attribute__((ext_vector_type(8)));
typedef float  floatx4 __attribute__((ext_vector_type(4)));
typedef unsigned long long u64;

// ws layout (bytes)
#define ECNT_OFF   0                                  // u32[64*384]   98304
#define GRPWIN_OFF 98304                              // u64[64*384*6] 1179648
#define EXTRA_OFF  (GRPWIN_OFF + 1179648)             // u64[64*384*12] 2359296
#define DST_OFF    (EXTRA_OFF + 2359296)              // int[64*NA]

__device__ __forceinline__ u64 shfl_xor_u64(u64 v, int msk) {
  unsigned int lo = (unsigned int)v, hi = (unsigned int)(v >> 32);
  lo = __shfl_xor(lo, msk, 64);
  hi = __shfl_xor(hi, msk, 64);
  return ((u64)hi << 32) | (u64)lo;
}
__device__ __forceinline__ double shfl_xor_f64(double v, int msk) {
  u64 u = __double_as_longlong(v);
  return __longlong_as_double((long long)shfl_xor_u64(u, msk));
}

__device__ __forceinline__ unsigned int fkey(float s) {
  unsigned int fb = __float_as_uint(s);
  return (fb & 0x80000000u) ? ~fb : (fb | 0x80000000u);
}
__device__ __forceinline__ float keyf(unsigned int k) {
  return (k & 0x80000000u) ? __uint_as_float(k ^ 0x80000000u) : __uint_as_float(~k);
}
__device__ __forceinline__ u64 packsc(float s, int col) {
  return ((u64)fkey(s) << 32) | (u64)(0xFFFFFFFFu - (unsigned int)col);
}
__device__ __forceinline__ int pcol(u64 p) {
  return (int)(0xFFFFFFFFu - (unsigned int)(p & 0xFFFFFFFFull));
}
__device__ __forceinline__ float pscore(u64 p) { return keyf((unsigned int)(p >> 32)); }

// two f32 -> two truncated bf16 packed in one dword
__device__ __forceinline__ unsigned int pk_bf16_trunc(unsigned int e1, unsigned int e0) {
  return __builtin_amdgcn_perm(e1, e0, 0x07060302u);
}

__device__ __forceinline__ void load16f(const float* x, size_t off, float* v) {
  const float4* p = (const float4*)(x + off);
  float4 a = p[0], b = p[1], c = p[2], d = p[3];
  v[0]=a.x; v[1]=a.y; v[2]=a.z; v[3]=a.w;
  v[4]=b.x; v[5]=b.y; v[6]=b.z; v[7]=b.w;
  v[8]=c.x; v[9]=c.y; v[10]=c.z; v[11]=c.w;
  v[12]=d.x; v[13]=d.y; v[14]=d.z; v[15]=d.w;
}

// ---------------------------------------------------------------------------
// k_scores: grid (64, 4 row-tiles, 3 col-tiles), 256 thr. 96x96 tile, BK=64,
// 16 chunks, double-buffered LDS. XOR swizzle: physical slot s of LDS row r
// holds k-granule s^(r&7) (granule = 8 bf16 = 16B) -> conflict-free
// ds_read_b128 (verified: 0 conflicts R4/R5). Same-batch blocks share
// linear%8 -> same XCD (64*y and 256*z are 0 mod 8).
// Wave w: i-tiles (w>>1)*3..+2, j-tiles (w&1)*3..+2, 9 accs.
// A/B frag: row/col = lane&15, k=(lane>>4)*8+e. C/D: col=lane&15,
// row=(lane>>4)*4+reg  [m89/m91].
// ---------------------------------------------------------------------------
__global__ __launch_bounds__(256, 2) void k_scores(const float* __restrict__ x,
                                                   u64* __restrict__ grpwin,
                                                   unsigned int* __restrict__ ecnt,
                                                   u64* __restrict__ extras) {
  __shared__ unsigned char smem[2][24576];  // per buf: A 96x128B @0, B @12288
  __shared__ float sumsq[96];
  int tid = threadIdx.x;
  int b  = blockIdx.x;
  int rt = blockIdx.y;                      // 0..3
  int ct = blockIdx.z;                      // 0..2
  int wv = tid >> 6, lane = tid & 63;
  int m = lane & 15, q = lane >> 4;
  int sw = m & 7;

  if (tid < 96) sumsq[tid] = 0.f;

  // fixed staging assignment: entry e -> v = tid + 256e; e>=3 are B rows
  const float* eptr[6];
  int eoff[6];
#pragma unroll
  for (int e = 0; e < 6; ++e) {
    int v = tid + 256 * e;
    int isB = v >= 768;
    int w = isB ? v - 768 : v;
    int row = w >> 3, slot = w & 7;
    int gk = slot ^ (row & 7);
    int tok;
    if (isB) tok = 2 * (ct * 96 + row) + 1;
    else { tok = 2 * (rt * 96 + row); if (tok > 576) tok = 576; }
    eptr[e] = x + (size_t)(b * T_ + tok) * C_ + gk * 8;
    eoff[e] = (isB ? 12288 : 0) + row * 128 + slot * 16;
  }

  float ssp[3] = {0.f, 0.f, 0.f};
  uint4 L[6][2];

  // prologue: load + stage chunk 0 into buf 0
#pragma unroll
  for (int e = 0; e < 6; ++e) {
    const uint4* p = (const uint4*)(eptr[e]);
    L[e][0] = p[0]; L[e][1] = p[1];
  }
#pragma unroll
  for (int e = 0; e < 6; ++e) {
    uint4 lo = L[e][0], hi = L[e][1];
    uint4 o;
    o.x = pk_bf16_trunc(lo.y, lo.x);
    o.y = pk_bf16_trunc(lo.w, lo.z);
    o.z = pk_bf16_trunc(hi.y, hi.x);
    o.w = pk_bf16_trunc(hi.w, hi.z);
    *(uint4*)(smem[0] + eoff[e]) = o;
    if (e >= 3) {
      float f0 = __uint_as_float(lo.x), f1 = __uint_as_float(lo.y);
      float f2 = __uint_as_float(lo.z), f3 = __uint_as_float(lo.w);
      float f4 = __uint_as_float(hi.x), f5 = __uint_as_float(hi.y);
      float f6 = __uint_as_float(hi.z), f7 = __uint_as_float(hi.w);
      ssp[e-3] += f0*f0 + f1*f1 + f2*f2 + f3*f3 + f4*f4 + f5*f5 + f6*f6 + f7*f7;
    }
  }
  __syncthreads();

  floatx4 acc[3][3];
#pragma unroll
  for (int ii = 0; ii < 3; ++ii)
#pragma unroll
    for (int jj = 0; jj < 3; ++jj) acc[ii][jj] = (floatx4){0,0,0,0};

  const int ib = (wv >> 1) * 3;
  const int jb = (wv & 1) * 3;

  for (int kc = 0; kc < 16; ++kc) {
    const unsigned char* buf = smem[kc & 1];
    unsigned char* nbuf = smem[(kc + 1) & 1];
    // issue next chunk's loads first; they land during the MFMA phase
    if (kc < 15) {
#pragma unroll
      for (int e = 0; e < 6; ++e) {
        const uint4* p = (const uint4*)(eptr[e] + (kc + 1) * 64);
        L[e][0] = p[0]; L[e][1] = p[1];
      }
    }
    // compute chunk kc from buf
#pragma unroll
    for (int s = 0; s < 2; ++s) {
      int slot = (s * 4 + q) ^ sw;
      bf16x8 af[3], bf[3];
#pragma unroll
      for (int ii = 0; ii < 3; ++ii)
        af[ii] = *(const bf16x8*)(buf + ((ib + ii) * 16 + m) * 128 + slot * 16);
#pragma unroll
      for (int jj = 0; jj < 3; ++jj)
        bf[jj] = *(const bf16x8*)(buf + 12288 + ((jb + jj) * 16 + m) * 128 + slot * 16);
#pragma unroll
      for (int ii = 0; ii < 3; ++ii)
#pragma unroll
        for (int jj = 0; jj < 3; ++jj)
          acc[ii][jj] = __builtin_amdgcn_mfma_f32_16x16x32_bf16(af[ii], bf[jj], acc[ii][jj], 0,0,0);
    }
    // stage chunk kc+1 into the other buffer
    if (kc < 15) {
#pragma unroll
      for (int e = 0; e < 6; ++e) {
        uint4 lo = L[e][0], hi = L[e][1];
        uint4 o;
        o.x = pk_bf16_trunc(lo.y, lo.x);
        o.y = pk_bf16_trunc(lo.w, lo.z);
        o.z = pk_bf16_trunc(hi.y, hi.x);
        o.w = pk_bf16_trunc(hi.w, hi.z);
        *(uint4*)(nbuf + eoff[e]) = o;
        if (e >= 3) {
          float f0 = __uint_as_float(lo.x), f1 = __uint_as_float(lo.y);
          float f2 = __uint_as_float(lo.z), f3 = __uint_as_float(lo.w);
          float f4 = __uint_as_float(hi.x), f5 = __uint_as_float(hi.y);
          float f6 = __uint_as_float(hi.z), f7 = __uint_as_float(hi.w);
          ssp[e-3] += f0*f0 + f1*f1 + f2*f2 + f3*f3 + f4*f4 + f5*f5 + f6*f6 + f7*f7;
        }
      }
    }
    __syncthreads();
  }

  // fold sumsq partials (3 fixed B-rows per thread, 8 threads per row)
#pragma unroll
  for (int e = 3; e < 6; ++e) {
    int w = tid + 256 * e - 768;
    atomicAdd(&sumsq[w >> 3], ssp[e-3]);
  }
  __syncthreads();

  // epilogue: normalize, per-row argmax over this wave's 48 cols
  float rn[3];
#pragma unroll
  for (int jj = 0; jj < 3; ++jj) rn[jj] = rsqrtf(sumsq[(jb + jj) * 16 + m]);

  int g = ct * 2 + (wv & 1);                // col-group id 0..5
#pragma unroll
  for (int ii = 0; ii < 3; ++ii) {
#pragma unroll
    for (int r = 0; r < 4; ++r) {
      u64 pj[3];
#pragma unroll
      for (int jj = 0; jj < 3; ++jj) {
        float s = acc[ii][jj][r] * rn[jj];
        pj[jj] = packsc(s, ct * 96 + (jb + jj) * 16 + m);
      }
      u64 pk = pj[0];
      if (pj[1] > pk) pk = pj[1];
      if (pj[2] > pk) pk = pj[2];
#pragma unroll
      for (int d = 1; d < 16; d <<= 1) {
        u64 o = shfl_xor_u64(pk, d);
        if (o > pk) pk = o;
      }
      int grow = rt * 96 + (ib + ii) * 16 + q * 4 + r;
      float thr = pscore(pk) - EPS_MARGIN;
      size_t rbase = (size_t)b * RPAD + grow;
#pragma unroll
      for (int jj = 0; jj < 3; ++jj) {
        if (pj[jj] != pk && pscore(pj[jj]) >= thr) {
          unsigned int idx = atomicAdd(&ecnt[rbase], 1u);
          if (idx < EXTRA_CAP) extras[rbase * EXTRA_CAP + idx] = pj[jj];
        }
      }
      if (m == 0) grpwin[rbase * 6 + g] = pk;
    }
  }
}

// ---------------------------------------------------------------------------
// k_recheck: wave per row i in [1,288]. Stage-1 max over 6 group winners;
// candidates = winners+extras within EPS. 1 candidate -> done. Else exact
// f64 dot/||b|| per candidate (tie -> lowest col).
// ---------------------------------------------------------------------------
__global__ __launch_bounds__(256) void k_recheck(const float* __restrict__ x,
                                                 const u64* __restrict__ grpwin,
                                                 const unsigned int* __restrict__ ecnt,
                                                 const u64* __restrict__ extras,
                                                 int* __restrict__ dst) {
  int wid = threadIdx.x >> 6, lane = threadIdx.x & 63;
  int gw = blockIdx.x * 4 + wid;            // grid = B*NB/4
  int b = gw / NB, i = gw - b * NB + 1;     // i in [1,288]
  size_t rbase = (size_t)b * RPAD + i;

  u64 v = (lane < 6) ? grpwin[rbase * 6 + lane] : 0ull;
#pragma unroll
  for (int d = 1; d < 8; d <<= 1) {
    u64 o = shfl_xor_u64(v, d);
    if (o > v) v = o;
  }
  {
    unsigned int lo = (unsigned int)v, hi = (unsigned int)(v >> 32);
    lo = __shfl(lo, 0, 64); hi = __shfl(hi, 0, 64);
    v = ((u64)hi << 32) | lo;
  }
  float thr = pscore(v) - EPS_MARGIN;

  u64 cand[14]; int nc = 0;
#pragma unroll
  for (int t = 0; t < 6; ++t) {
    u64 w = grpwin[rbase * 6 + t];
    if (pscore(w) >= thr && nc < 14) cand[nc++] = w;
  }
  unsigned int ec = ecnt[rbase]; if (ec > EXTRA_CAP) ec = EXTRA_CAP;
  for (unsigned int t = 0; t < ec; ++t) {
    u64 w = extras[rbase * EXTRA_CAP + t];
    if (pscore(w) >= thr && nc < 14) cand[nc++] = w;
  }

  int best;
  if (nc <= 1) {
    best = pcol(v);
  } else {
    float av[16];
    load16f(x, (size_t)(b * T_ + 2 * i) * C_ + lane * 16, av);
    double bs = -1e300; int bc = 1 << 30;
    for (int c = 0; c < nc; ++c) {
      int col = pcol(cand[c]);
      float bv[16];
      load16f(x, (size_t)(b * T_ + 2 * col + 1) * C_ + lane * 16, bv);
      double dot = 0.0, nsq = 0.0;
#pragma unroll
      for (int t = 0; t < 16; ++t) {
        dot += (double)av[t] * (double)bv[t];
        nsq += (double)bv[t] * (double)bv[t];
      }
#pragma unroll
      for (int d = 32; d >= 1; d >>= 1) {
        dot += shfl_xor_f64(dot, d);
        nsq += shfl_xor_f64(nsq, d);
      }
      double s = dot / sqrt(nsq);
      if (s > bs || (s == bs && col < bc)) { bs = s; bc = col; }
    }
    best = bc;
  }
  if (lane == 0) dst[b * NA + i] = best;
}

// ---------------------------------------------------------------------------
// k_merge: membership lists in LDS, wave per output row.
// ---------------------------------------------------------------------------
__global__ __launch_bounds__(256) void k_merge(const float* __restrict__ x,
                                               const int* __restrict__ dst,
                                               float* __restrict__ out) {
  __shared__ int dstv[NA];
  __shared__ unsigned short lists[4][292];
  __shared__ int cnts[4];
  int b = blockIdx.y, tid = threadIdx.x;
  int orow_base = blockIdx.x * 4;

  for (int i = tid; i < NA; i += 256) dstv[i] = (i >= 1) ? dst[b * NA + i] : -1;
  if (tid < 4) cnts[tid] = 0;
  __syncthreads();

  for (int i = 1 + tid; i <= 288; i += 256) {
    int d = dstv[i];
#pragma unroll
    for (int w4 = 0; w4 < 4; ++w4) {
      int orow_w = orow_base + w4;
      if (orow_w >= 1 && orow_w < NA && d == orow_w - 1) {
        int idx = atomicAdd(&cnts[w4], 1);
        lists[w4][idx] = (unsigned short)i;
      }
    }
  }
  __syncthreads();

  int wv = tid >> 6, lane = tid & 63;
  int orow = orow_base + wv;
  if (orow >= NA) return;

  const size_t xb = (size_t)b * T_ * C_;
  int c0 = lane * 16;
  float acc[16];
  float inv = 1.0f;

  if (orow == 0) {
    load16f(x, xb + c0, acc);
  } else {
    int j = orow - 1;
    load16f(x, xb + (size_t)(2 * j + 1) * C_ + c0, acc);
    int cnt = cnts[wv];
    for (int e = 0; e < cnt; ++e) {
      int i = lists[wv][e];
      float tv[16];
      load16f(x, xb + (size_t)(2 * i) * C_ + c0, tv);
#pragma unroll
      for (int t = 0; t < 16; ++t) acc[t] += tv[t];
    }
    inv = 1.0f / (float)(cnt + 1);
  }

  float4* op = (float4*)(out + ((size_t)b * NA + orow) * C_ + c0);
  op[0] = make_float4(acc[0]*inv,  acc[1]*inv,  acc[2]*inv,  acc[3]*inv);
  op[1] = make_float4(acc[4]*inv,  acc[5]*inv,  acc[6]*inv,  acc[7]*inv);
  op[2] = make_float4(acc[8]*inv,  acc[9]*inv,  acc[10]*inv, acc[11]*inv);
  op[3] = make_float4(acc[12]*inv, acc[13]*inv, acc[14]*inv, acc[15]*inv);
}

// ---------------------------------------------------------------------------
extern "C" void kernel_launch(void* const* d_in, const int* in_sizes, int n_in,
                              void* d_out, int out_size, void* d_ws, size_t ws_size,
                              hipStream_t stream) {
  const float* x = (const float*)d_in[0];
  float* out     = (float*)d_out;
  char* ws = (char*)d_ws;
  unsigned int* ecnt = (unsigned int*)(ws + ECNT_OFF);
  u64* grpwin        = (u64*)(ws + GRPWIN_OFF);
  u64* extras        = (u64*)(ws + EXTRA_OFF);
  int* dst           = (int*)(ws + DST_OFF);

  hipMemsetAsync(ecnt, 0, (size_t)B_ * RPAD * sizeof(unsigned int), stream);
  k_scores <<<dim3(B_, 4, 3), 256, 0, stream>>>(x, grpwin, ecnt, extras);
  k_recheck<<<B_ * NB / 4, 256, 0, stream>>>(x, grpwin, ecnt, extras, dst);
  k_merge  <<<dim3((NA + 3) / 4, B_), 256, 0, stream>>>(x, dst, out);
}